// Round 2
// baseline (7390.413 us; speedup 1.0000x reference)
//
#include <hip/hip_runtime.h>
#include <hip/hip_bf16.h>

#define NN 100000
#define EE 1600000
#define HH 128
#define NDIM 91
#define EDIM 20
#define BB 128
#define EPSF 1e-5f
#define CHUNK 131072

// ---------------- embed: h = nf @ W + b  (N x 91 @ 91 x 128) ----------------
__global__ __launch_bounds__(256) void k_embed(const float* __restrict__ nf,
                                               const float* __restrict__ W,
                                               const float* __restrict__ b,
                                               float* __restrict__ h) {
  __shared__ float w_s[NDIM * HH];   // 46.6 KB
  __shared__ float b_s[HH];
  __shared__ float a_s[16 * 92];     // 5.9 KB (padded rows)
  for (int i = threadIdx.x; i < NDIM * HH; i += 256) w_s[i] = W[i];
  if (threadIdx.x < HH) b_s[threadIdx.x] = b[threadIdx.x];
  __syncthreads();
  int col = threadIdx.x & 127, rs = threadIdx.x >> 7;
  for (int base = blockIdx.x * 16; base < NN; base += gridDim.x * 16) {
    int nrows = min(16, NN - base);
    int tot = nrows * NDIM;
    for (int i = threadIdx.x; i < tot; i += 256) {
      int r = i / NDIM;
      a_s[r * 92 + (i - r * NDIM)] = nf[(size_t)base * NDIM + i];
    }
    __syncthreads();
    float acc[8];
#pragma unroll
    for (int r = 0; r < 8; r++) acc[r] = 0.f;
    for (int k = 0; k < NDIM; k++) {
      float w = w_s[k * HH + col];
#pragma unroll
      for (int r = 0; r < 8; r++) acc[r] += a_s[(rs * 8 + r) * 92 + k] * w;
    }
#pragma unroll
    for (int r = 0; r < 8; r++) {
      int row = base + rs * 8 + r;
      if (row < NN) h[(size_t)row * HH + col] = acc[r] + b_s[col];
    }
    __syncthreads();
  }
}

// ------------- node_mm: hs = h@Wsrc, hd = h@Wdst  (bf16 out) ---------------
__global__ __launch_bounds__(256) void k_node_mm(const float* __restrict__ h,
                                                 const float* __restrict__ Wsrc,
                                                 const float* __restrict__ Wdst,
                                                 __hip_bfloat16* __restrict__ hs,
                                                 __hip_bfloat16* __restrict__ hd) {
  __shared__ float w_s[HH * 64];   // 32 KB
  __shared__ float a_s[32 * HH];   // 16 KB
  const float* W = (blockIdx.y < 4) ? Wsrc : Wdst;
  __hip_bfloat16* out = (blockIdx.y < 4) ? hs : hd;
  int coff = (blockIdx.y & 3) * 64;
  for (int i = threadIdx.x; i < HH * 64; i += 256) {
    int k = i >> 6, c = i & 63;
    w_s[i] = W[k * 256 + coff + c];
  }
  __syncthreads();
  int col = threadIdx.x & 63, rs = threadIdx.x >> 6;  // rs in 0..3
  for (int base = blockIdx.x * 32; base < NN; base += gridDim.x * 32) {
    int nrows = min(32, NN - base);
    for (int i = threadIdx.x; i < nrows * HH; i += 256) a_s[i] = h[(size_t)base * HH + i];
    __syncthreads();
    float acc[8];
#pragma unroll
    for (int r = 0; r < 8; r++) acc[r] = 0.f;
    for (int k = 0; k < HH; k++) {
      float w = w_s[k * 64 + col];
#pragma unroll
      for (int r = 0; r < 8; r++) acc[r] += a_s[(rs * 8 + r) * HH + k] * w;
    }
#pragma unroll
    for (int r = 0; r < 8; r++) {
      int row = base + rs * 8 + r;
      if (row < NN) out[(size_t)row * 256 + coff + col] = __float2bfloat16(acc[r]);
    }
    __syncthreads();
  }
}

// ---- ez = ef @ We + b  for a chunk of edges, output bf16 (chunk-local) -----
// 256 thr: thread owns 2 adjacent cols (c2,c2+1); weights in 40 registers.
// Block processes 32 edges; ef tile staged in LDS, read as broadcast float4.
__global__ __launch_bounds__(256) void k_ez(const float* __restrict__ ef,
                                            const float* __restrict__ We,
                                            const float* __restrict__ bias,
                                            __hip_bfloat16* __restrict__ ez,
                                            int e0, int ne) {
  __shared__ float ef_s[32 * EDIM];
  int c2 = (threadIdx.x & 127) * 2;
  float w0[EDIM], w1[EDIM];
#pragma unroll
  for (int k = 0; k < EDIM; k++) {
    float2 wk = *(const float2*)&We[k * 256 + c2];
    w0[k] = wk.x; w1[k] = wk.y;
  }
  float2 bb = *(const float2*)&bias[c2];
  int base = blockIdx.x * 32;
  if (base >= ne) return;
  int nEd = min(32, ne - base);
  for (int i = threadIdx.x; i < nEd * EDIM; i += 256)
    ef_s[i] = ef[(size_t)(e0 + base) * EDIM + i];
  __syncthreads();
  int sub = threadIdx.x >> 7;  // 0..1, 16 edges each
  int rend = min(nEd, sub * 16 + 16);
  for (int r = sub * 16; r < rend; r++) {
    const float4* evr = (const float4*)&ef_s[r * EDIM];
    float za = bb.x, zb = bb.y;
#pragma unroll
    for (int q = 0; q < 5; q++) {
      float4 ev = evr[q];
      za += ev.x * w0[q * 4] + ev.y * w0[q * 4 + 1] + ev.z * w0[q * 4 + 2] + ev.w * w0[q * 4 + 3];
      zb += ev.x * w1[q * 4] + ev.y * w1[q * 4 + 1] + ev.z * w1[q * 4 + 2] + ev.w * w1[q * 4 + 3];
    }
    __hip_bfloat162 o;
    o.x = __float2bfloat16(za); o.y = __float2bfloat16(zb);
    *(__hip_bfloat162*)&ez[(size_t)(base + r) * 256 + c2] = o;
  }
}

__device__ __forceinline__ float softplus_f(float z) {
  float t = __expf(-fabsf(z));
  float l = __logf(1.f + t);
  return (z > 0.f) ? z + l : l;
}

// ---- edge kernel (slim): z = hs[src]+hd[dst]+ez ; msg=sig(z1)*softplus(z2);
// ---- atomicAdd into agg[dst].  64-lane group per edge, 2 cols/lane.
__global__ __launch_bounds__(256) void k_edge(const __hip_bfloat16* __restrict__ hs,
                                              const __hip_bfloat16* __restrict__ hd,
                                              const __hip_bfloat16* __restrict__ ez,
                                              const int* __restrict__ src,
                                              const int* __restrict__ dst,
                                              float* __restrict__ agg,
                                              int e0, int ne) {
  int lane = threadIdx.x & 63;
  int grp = threadIdx.x >> 6;
  int c2 = lane * 2;
  int slot = blockIdx.x * 4 + grp;
  int nslot = gridDim.x * 4;
  for (int e = slot; e < ne; e += nslot) {
    int ge = e0 + e;
    int s = src[ge], d = dst[ge];
    __hip_bfloat162 g0 = *(const __hip_bfloat162*)&hs[(size_t)s * 256 + c2];
    __hip_bfloat162 g1 = *(const __hip_bfloat162*)&hs[(size_t)s * 256 + 128 + c2];
    __hip_bfloat162 g2 = *(const __hip_bfloat162*)&hd[(size_t)d * 256 + c2];
    __hip_bfloat162 g3 = *(const __hip_bfloat162*)&hd[(size_t)d * 256 + 128 + c2];
    __hip_bfloat162 z0 = *(const __hip_bfloat162*)&ez[(size_t)e * 256 + c2];
    __hip_bfloat162 z1 = *(const __hip_bfloat162*)&ez[(size_t)e * 256 + 128 + c2];
    float za0 = __bfloat162float(g0.x) + __bfloat162float(g2.x) + __bfloat162float(z0.x);
    float za1 = __bfloat162float(g0.y) + __bfloat162float(g2.y) + __bfloat162float(z0.y);
    float zb0 = __bfloat162float(g1.x) + __bfloat162float(g3.x) + __bfloat162float(z1.x);
    float zb1 = __bfloat162float(g1.y) + __bfloat162float(g3.y) + __bfloat162float(z1.y);
    float m0 = __fdividef(softplus_f(zb0), 1.f + __expf(-za0));
    float m1 = __fdividef(softplus_f(zb1), 1.f + __expf(-za1));
    atomicAdd(&agg[(size_t)d * HH + c2], m0);
    atomicAdd(&agg[(size_t)d * HH + c2 + 1], m1);
  }
}

// ---------------- BN stats: per-column sum & sumsq over N rows --------------
__global__ __launch_bounds__(256) void k_bn_stats(const float* __restrict__ agg,
                                                  float* __restrict__ stats) {
  int col = threadIdx.x & 127, half = threadIdx.x >> 7;
  float s = 0.f, sq = 0.f;
  for (int row = blockIdx.x * 2 + half; row < NN; row += gridDim.x * 2) {
    float v = agg[(size_t)row * HH + col];
    s += v; sq += v * v;
  }
  __shared__ float ls[256], lq[256];
  ls[threadIdx.x] = s; lq[threadIdx.x] = sq;
  __syncthreads();
  if (half == 0) {
    atomicAdd(&stats[col], ls[col] + ls[col + 128]);
    atomicAdd(&stats[128 + col], lq[col] + lq[col + 128]);
  }
}

__global__ void k_bn_fin(float* stats, const float* __restrict__ gam,
                         const float* __restrict__ bet) {
  int c = threadIdx.x;
  if (c >= HH) return;
  float mean = stats[c] / (float)NN;
  float var = stats[HH + c] / (float)NN - mean * mean;
  float sc = rsqrtf(var + EPSF) * gam[c];
  stats[c] = sc;
  stats[HH + c] = bet[c] - mean * sc;
}

// ---------------- h = relu(h + agg*scale + shift) ---------------------------
__global__ __launch_bounds__(256) void k_update(float* __restrict__ h,
                                                const float* __restrict__ agg,
                                                const float* __restrict__ stats) {
  for (size_t i = (size_t)blockIdx.x * blockDim.x + threadIdx.x; i < (size_t)NN * HH;
       i += (size_t)gridDim.x * blockDim.x) {
    int c = (int)(i & 127);
    float v = h[i] + agg[i] * stats[c] + stats[128 + c];
    h[i] = fmaxf(v, 0.f);
  }
}

// ---------------- pooling: contiguous chunk per block, register acc ---------
__global__ void k_pool(const float* __restrict__ h, const int* __restrict__ batch,
                       float* __restrict__ g, float* __restrict__ gcnt) {
  int col = threadIdx.x;  // 128
  int chunk = (NN + gridDim.x - 1) / gridDim.x;
  int n0 = blockIdx.x * chunk, n1 = min(NN, n0 + chunk);
  if (n0 >= n1) return;
  int cur = batch[n0];
  float acc = 0.f, cnt = 0.f;
  for (int n = n0; n < n1; n++) {
    int bb = batch[n];
    if (bb != cur) {
      atomicAdd(&g[cur * HH + col], acc);
      if (col == 0) atomicAdd(&gcnt[cur], cnt);
      acc = 0.f; cnt = 0.f; cur = bb;
    }
    acc += h[(size_t)n * HH + col];
    cnt += 1.f;
  }
  atomicAdd(&g[cur * HH + col], acc);
  if (col == 0) atomicAdd(&gcnt[cur], cnt);
}

// ---------------- final head: mean-pool norm, fc1, BN, relu, out ------------
__global__ __launch_bounds__(256) void k_final(float* __restrict__ g,
                                               const float* __restrict__ gcnt,
                                               const float* __restrict__ fc1w,
                                               const float* __restrict__ fc1b,
                                               const float* __restrict__ gam,
                                               const float* __restrict__ bet,
                                               const float* __restrict__ ow,
                                               const float* __restrict__ ob,
                                               float* __restrict__ out) {
  __shared__ float w_s[HH * HH];  // 64 KB
  __shared__ float y_s[BB * HH];  // 64 KB
  __shared__ float ls[256], lq[256];
  for (int i = threadIdx.x; i < HH * HH; i += 256) w_s[i] = fc1w[i];
  for (int i = threadIdx.x; i < BB * HH; i += 256) {
    int r = i >> 7;
    g[i] = g[i] / fmaxf(gcnt[r], 1.f);
  }
  __syncthreads();
  int c = threadIdx.x & 127, h2 = threadIdx.x >> 7;
  for (int rr = 0; rr < 64; rr++) {
    int r = h2 * 64 + rr;
    float acc = fc1b[c];
    for (int k = 0; k < HH; k++) acc += g[r * HH + k] * w_s[k * HH + c];
    y_s[r * HH + c] = acc;
  }
  __syncthreads();
  float s = 0.f, sq = 0.f;
  for (int rr = 0; rr < 64; rr++) {
    float v = y_s[(h2 * 64 + rr) * HH + c];
    s += v; sq += v * v;
  }
  ls[threadIdx.x] = s; lq[threadIdx.x] = sq;
  __syncthreads();
  if (h2 == 0) {
    float ss = ls[c] + ls[c + 128], qq = lq[c] + lq[c + 128];
    float mean = ss / (float)BB, var = qq / (float)BB - mean * mean;
    float sc = rsqrtf(var + EPSF) * gam[c];
    ls[c] = sc;
    lq[c] = bet[c] - mean * sc;
  }
  __syncthreads();
  for (int rr = 0; rr < 64; rr++) {
    int r = h2 * 64 + rr;
    y_s[r * HH + c] = fmaxf(y_s[r * HH + c] * ls[c] + lq[c], 0.f);
  }
  __syncthreads();
  int r2 = threadIdx.x >> 1, hf = threadIdx.x & 1;
  float acc = 0.f;
  for (int k = hf * 64; k < hf * 64 + 64; k++) acc += y_s[r2 * HH + k] * ow[k];
  __syncthreads();
  ls[threadIdx.x] = acc;
  __syncthreads();
  if (hf == 0) out[r2] = ls[threadIdx.x] + ls[threadIdx.x + 1] + ob[0];
}

extern "C" void kernel_launch(void* const* d_in, const int* in_sizes, int n_in,
                              void* d_out, int out_size, void* d_ws, size_t ws_size,
                              hipStream_t stream) {
  (void)in_sizes; (void)n_in; (void)out_size; (void)ws_size;
  const float* node_feats = (const float*)d_in[0];
  const int* edge_index = (const int*)d_in[1];
  const float* edge_feats = (const float*)d_in[2];
  const int* batch = (const int*)d_in[3];
  const float* embed_w = (const float*)d_in[4];
  const float* embed_b = (const float*)d_in[5];
  const float* conv_wsrc = (const float*)d_in[6];
  const float* conv_wdst = (const float*)d_in[7];
  const float* conv_we = (const float*)d_in[8];
  const float* conv_b = (const float*)d_in[9];
  const float* bn_gamma = (const float*)d_in[10];
  const float* bn_beta = (const float*)d_in[11];
  const float* fc1_w = (const float*)d_in[12];
  const float* fc1_b = (const float*)d_in[13];
  const float* fc_bn_gamma = (const float*)d_in[14];
  const float* fc_bn_beta = (const float*)d_in[15];
  const float* out_w = (const float*)d_in[16];
  const float* out_b = (const float*)d_in[17];

  char* ws = (char*)d_ws;
  size_t o = 0;
  float* h = (float*)(ws + o);            o += (size_t)NN * HH * 4;       // 51.2 MB
  __hip_bfloat16* hs = (__hip_bfloat16*)(ws + o); o += (size_t)NN * 256 * 2;  // 51.2 MB
  __hip_bfloat16* hd = (__hip_bfloat16*)(ws + o); o += (size_t)NN * 256 * 2;  // 51.2 MB
  float* agg = (float*)(ws + o);          o += (size_t)NN * HH * 4;       // 51.2 MB
  __hip_bfloat16* ez = (__hip_bfloat16*)(ws + o); o += (size_t)CHUNK * 256 * 2; // 64 MB
  float* stats = (float*)(ws + o);        o += 256 * 4;
  float* g = (float*)(ws + o);            o += (size_t)BB * HH * 4;
  float* gcnt = (float*)(ws + o);         o += BB * 4;

  k_embed<<<512, 256, 0, stream>>>(node_feats, embed_w, embed_b, h);

  for (int i = 0; i < 3; i++) {
    k_node_mm<<<dim3(256, 8), 256, 0, stream>>>(h, conv_wsrc + (size_t)i * HH * 256,
                                                conv_wdst + (size_t)i * HH * 256, hs, hd);
    hipMemsetAsync(agg, 0, (size_t)NN * HH * 4, stream);
    hipMemsetAsync(stats, 0, 256 * 4, stream);
    for (int c0 = 0; c0 < EE; c0 += CHUNK) {
      int ne = (EE - c0 < CHUNK) ? (EE - c0) : CHUNK;
      k_ez<<<(ne + 31) / 32, 256, 0, stream>>>(edge_feats,
                                               conv_we + (size_t)i * EDIM * 256,
                                               conv_b + (size_t)i * 256, ez, c0, ne);
      k_edge<<<4096, 256, 0, stream>>>(hs, hd, ez, edge_index, edge_index + EE,
                                       agg, c0, ne);
    }
    k_bn_stats<<<1024, 256, 0, stream>>>(agg, stats);
    k_bn_fin<<<1, 128, 0, stream>>>(stats, bn_gamma + i * HH, bn_beta + i * HH);
    k_update<<<2048, 256, 0, stream>>>(h, agg, stats);
  }

  hipMemsetAsync(g, 0, (size_t)BB * HH * 4, stream);
  hipMemsetAsync(gcnt, 0, BB * 4, stream);
  k_pool<<<256, 128, 0, stream>>>(h, batch, g, gcnt);
  k_final<<<1, 256, 0, stream>>>(g, gcnt, fc1_w, fc1_b, fc_bn_gamma, fc_bn_beta,
                                 out_w, out_b, (float*)d_out);
}

// Round 3
// 4111.893 us; speedup vs baseline: 1.7973x; 1.7973x over previous
//
#include <hip/hip_runtime.h>
#include <hip/hip_bf16.h>

#define NN 100000
#define EE 1600000
#define HH 128
#define NDIM 91
#define EDIM 20
#define BB 128
#define EPSF 1e-5f

// ---------------- embed: h = nf @ W + b  (N x 91 @ 91 x 128) ----------------
__global__ __launch_bounds__(256) void k_embed(const float* __restrict__ nf,
                                               const float* __restrict__ W,
                                               const float* __restrict__ b,
                                               float* __restrict__ h) {
  __shared__ float w_s[NDIM * HH];
  __shared__ float b_s[HH];
  __shared__ float a_s[16 * 92];
  for (int i = threadIdx.x; i < NDIM * HH; i += 256) w_s[i] = W[i];
  if (threadIdx.x < HH) b_s[threadIdx.x] = b[threadIdx.x];
  __syncthreads();
  int col = threadIdx.x & 127, rs = threadIdx.x >> 7;
  for (int base = blockIdx.x * 16; base < NN; base += gridDim.x * 16) {
    int nrows = min(16, NN - base);
    int tot = nrows * NDIM;
    for (int i = threadIdx.x; i < tot; i += 256) {
      int r = i / NDIM;
      a_s[r * 92 + (i - r * NDIM)] = nf[(size_t)base * NDIM + i];
    }
    __syncthreads();
    float acc[8];
#pragma unroll
    for (int r = 0; r < 8; r++) acc[r] = 0.f;
    for (int k = 0; k < NDIM; k++) {
      float w = w_s[k * HH + col];
#pragma unroll
      for (int r = 0; r < 8; r++) acc[r] += a_s[(rs * 8 + r) * 92 + k] * w;
    }
#pragma unroll
    for (int r = 0; r < 8; r++) {
      int row = base + rs * 8 + r;
      if (row < NN) h[(size_t)row * HH + col] = acc[r] + b_s[col];
    }
    __syncthreads();
  }
}

// ------------- node_mm: hs = h@Wsrc, hd = h@Wdst  (bf16 out) ---------------
__global__ __launch_bounds__(256) void k_node_mm(const float* __restrict__ h,
                                                 const float* __restrict__ Wsrc,
                                                 const float* __restrict__ Wdst,
                                                 __hip_bfloat16* __restrict__ hs,
                                                 __hip_bfloat16* __restrict__ hd) {
  __shared__ float w_s[HH * 64];
  __shared__ float a_s[32 * HH];
  const float* W = (blockIdx.y < 4) ? Wsrc : Wdst;
  __hip_bfloat16* out = (blockIdx.y < 4) ? hs : hd;
  int coff = (blockIdx.y & 3) * 64;
  for (int i = threadIdx.x; i < HH * 64; i += 256) {
    int k = i >> 6, c = i & 63;
    w_s[i] = W[k * 256 + coff + c];
  }
  __syncthreads();
  int col = threadIdx.x & 63, rs = threadIdx.x >> 6;
  for (int base = blockIdx.x * 32; base < NN; base += gridDim.x * 32) {
    int nrows = min(32, NN - base);
    for (int i = threadIdx.x; i < nrows * HH; i += 256) a_s[i] = h[(size_t)base * HH + i];
    __syncthreads();
    float acc[8];
#pragma unroll
    for (int r = 0; r < 8; r++) acc[r] = 0.f;
    for (int k = 0; k < HH; k++) {
      float w = w_s[k * 64 + col];
#pragma unroll
      for (int r = 0; r < 8; r++) acc[r] += a_s[(rs * 8 + r) * HH + k] * w;
    }
#pragma unroll
    for (int r = 0; r < 8; r++) {
      int row = base + rs * 8 + r;
      if (row < NN) out[(size_t)row * 256 + coff + col] = __float2bfloat16(acc[r]);
    }
    __syncthreads();
  }
}

// ---------------- counting sort by dst: hist, scan, scatter -----------------
__global__ __launch_bounds__(256) void k_hist(const int* __restrict__ dst,
                                              int* __restrict__ cnt) {
  for (int e = blockIdx.x * 256 + threadIdx.x; e < EE; e += gridDim.x * 256)
    atomicAdd(&cnt[dst[e]], 1);
}

__global__ __launch_bounds__(1024) void k_scan(const int* __restrict__ cnt,
                                               int* __restrict__ off) {
  __shared__ int ps[1024];
  int t = threadIdx.x;
  const int R = (NN + 1023) / 1024;  // 98
  int b0 = t * R, b1 = min(NN, b0 + R);
  int s = 0;
  for (int i = b0; i < b1; i++) s += cnt[i];
  ps[t] = s;
  __syncthreads();
  for (int d = 1; d < 1024; d <<= 1) {
    int v = (t >= d) ? ps[t - d] : 0;
    __syncthreads();
    ps[t] += v;
    __syncthreads();
  }
  int run = (t == 0) ? 0 : ps[t - 1];
  for (int i = b0; i < b1; i++) {
    off[i] = run;
    run += cnt[i];
  }
}

// scatter edge data into dst-sorted order; also permutes ef rows (80B each)
__global__ __launch_bounds__(256) void k_scatter(const int* __restrict__ src,
                                                 const int* __restrict__ dst,
                                                 const float* __restrict__ ef,
                                                 int* __restrict__ off,
                                                 int* __restrict__ src_s,
                                                 int* __restrict__ dst_s,
                                                 float* __restrict__ ef_s) {
  for (int e = blockIdx.x * 256 + threadIdx.x; e < EE; e += gridDim.x * 256) {
    int d = dst[e];
    int pos = atomicAdd(&off[d], 1);
    src_s[pos] = src[e];
    dst_s[pos] = d;
    const float4* in = (const float4*)&ef[(size_t)e * EDIM];
    float4* outp = (float4*)&ef_s[(size_t)pos * EDIM];
#pragma unroll
    for (int q = 0; q < 5; q++) outp[q] = in[q];
  }
}

__device__ __forceinline__ float softplus_f(float z) {
  float t = __expf(-fabsf(z));
  float l = __logf(1.f + t);
  return (z > 0.f) ? z + l : l;
}

// ---- sorted edge kernel: wave owns contiguous sorted-edge range.
// z = hs[src]+hd[dst]+ef@We+b ; msg=sig(z_lo)*softplus(z_hi); segment-accum
// in registers, flush via atomicAdd at segment/range boundaries.
__global__ __launch_bounds__(256) void k_edge_sorted(
    const __hip_bfloat16* __restrict__ hs, const __hip_bfloat16* __restrict__ hd,
    const float* __restrict__ ef_s, const int* __restrict__ src_s,
    const int* __restrict__ dst_s, const float* __restrict__ We,
    const float* __restrict__ bias, float* __restrict__ agg, int slots) {
  int lane = threadIdx.x & 63, wv = threadIdx.x >> 6;
  int slot = blockIdx.x * 4 + wv;
  int c2 = lane * 2;
  // We columns for this lane: gate cols (c2,c2+1), softplus cols (128+c2,+1)
  float wa0[EDIM], wa1[EDIM], wb0[EDIM], wb1[EDIM];
#pragma unroll
  for (int k = 0; k < EDIM; k++) {
    float2 a = *(const float2*)&We[k * 256 + c2];
    float2 b = *(const float2*)&We[k * 256 + 128 + c2];
    wa0[k] = a.x; wa1[k] = a.y; wb0[k] = b.x; wb1[k] = b.y;
  }
  float2 ba = *(const float2*)&bias[c2];
  float2 bb = *(const float2*)&bias[128 + c2];
  int per = (EE + slots - 1) / slots;
  int i0 = slot * per, i1 = min(EE, i0 + per);
  if (i0 >= i1) return;
  int cur = dst_s[i0];
  float hd00, hd01, hd10, hd11;
  {
    __hip_bfloat162 t0 = *(const __hip_bfloat162*)&hd[(size_t)cur * 256 + c2];
    __hip_bfloat162 t1 = *(const __hip_bfloat162*)&hd[(size_t)cur * 256 + 128 + c2];
    hd00 = __bfloat162float(t0.x); hd01 = __bfloat162float(t0.y);
    hd10 = __bfloat162float(t1.x); hd11 = __bfloat162float(t1.y);
  }
  float acc0 = 0.f, acc1 = 0.f;
  for (int i = i0; i < i1; i++) {
    int d = dst_s[i];
    if (d != cur) {  // wave-uniform branch
      atomicAdd(&agg[(size_t)cur * HH + c2], acc0);
      atomicAdd(&agg[(size_t)cur * HH + c2 + 1], acc1);
      acc0 = 0.f; acc1 = 0.f; cur = d;
      __hip_bfloat162 t0 = *(const __hip_bfloat162*)&hd[(size_t)cur * 256 + c2];
      __hip_bfloat162 t1 = *(const __hip_bfloat162*)&hd[(size_t)cur * 256 + 128 + c2];
      hd00 = __bfloat162float(t0.x); hd01 = __bfloat162float(t0.y);
      hd10 = __bfloat162float(t1.x); hd11 = __bfloat162float(t1.y);
    }
    int s = src_s[i];
    __hip_bfloat162 g0 = *(const __hip_bfloat162*)&hs[(size_t)s * 256 + c2];
    __hip_bfloat162 g1 = *(const __hip_bfloat162*)&hs[(size_t)s * 256 + 128 + c2];
    float za0 = ba.x + __bfloat162float(g0.x) + hd00;
    float za1 = ba.y + __bfloat162float(g0.y) + hd01;
    float zb0 = bb.x + __bfloat162float(g1.x) + hd10;
    float zb1 = bb.y + __bfloat162float(g1.y) + hd11;
    const float4* er = (const float4*)&ef_s[(size_t)i * EDIM];
#pragma unroll
    for (int q = 0; q < 5; q++) {
      float4 ev = er[q];
      za0 += ev.x * wa0[q*4] + ev.y * wa0[q*4+1] + ev.z * wa0[q*4+2] + ev.w * wa0[q*4+3];
      za1 += ev.x * wa1[q*4] + ev.y * wa1[q*4+1] + ev.z * wa1[q*4+2] + ev.w * wa1[q*4+3];
      zb0 += ev.x * wb0[q*4] + ev.y * wb0[q*4+1] + ev.z * wb0[q*4+2] + ev.w * wb0[q*4+3];
      zb1 += ev.x * wb1[q*4] + ev.y * wb1[q*4+1] + ev.z * wb1[q*4+2] + ev.w * wb1[q*4+3];
    }
    acc0 += __fdividef(softplus_f(zb0), 1.f + __expf(-za0));
    acc1 += __fdividef(softplus_f(zb1), 1.f + __expf(-za1));
  }
  atomicAdd(&agg[(size_t)cur * HH + c2], acc0);
  atomicAdd(&agg[(size_t)cur * HH + c2 + 1], acc1);
}

// ---------------- BN stats: per-column sum & sumsq over N rows --------------
__global__ __launch_bounds__(256) void k_bn_stats(const float* __restrict__ agg,
                                                  float* __restrict__ stats) {
  int col = threadIdx.x & 127, half = threadIdx.x >> 7;
  float s = 0.f, sq = 0.f;
  for (int row = blockIdx.x * 2 + half; row < NN; row += gridDim.x * 2) {
    float v = agg[(size_t)row * HH + col];
    s += v; sq += v * v;
  }
  __shared__ float ls[256], lq[256];
  ls[threadIdx.x] = s; lq[threadIdx.x] = sq;
  __syncthreads();
  if (half == 0) {
    atomicAdd(&stats[col], ls[col] + ls[col + 128]);
    atomicAdd(&stats[128 + col], lq[col] + lq[col + 128]);
  }
}

__global__ void k_bn_fin(float* stats, const float* __restrict__ gam,
                         const float* __restrict__ bet) {
  int c = threadIdx.x;
  if (c >= HH) return;
  float mean = stats[c] / (float)NN;
  float var = stats[HH + c] / (float)NN - mean * mean;
  float sc = rsqrtf(var + EPSF) * gam[c];
  stats[c] = sc;
  stats[HH + c] = bet[c] - mean * sc;
}

// ---------------- h = relu(h + agg*scale + shift) ---------------------------
__global__ __launch_bounds__(256) void k_update(float* __restrict__ h,
                                                const float* __restrict__ agg,
                                                const float* __restrict__ stats) {
  for (size_t i = (size_t)blockIdx.x * blockDim.x + threadIdx.x; i < (size_t)NN * HH;
       i += (size_t)gridDim.x * blockDim.x) {
    int c = (int)(i & 127);
    float v = h[i] + agg[i] * stats[c] + stats[128 + c];
    h[i] = fmaxf(v, 0.f);
  }
}

// ---------------- pooling: contiguous chunk per block, register acc ---------
__global__ void k_pool(const float* __restrict__ h, const int* __restrict__ batch,
                       float* __restrict__ g, float* __restrict__ gcnt) {
  int col = threadIdx.x;  // 128
  int chunk = (NN + gridDim.x - 1) / gridDim.x;
  int n0 = blockIdx.x * chunk, n1 = min(NN, n0 + chunk);
  if (n0 >= n1) return;
  int cur = batch[n0];
  float acc = 0.f, cnt = 0.f;
  for (int n = n0; n < n1; n++) {
    int bb = batch[n];
    if (bb != cur) {
      atomicAdd(&g[cur * HH + col], acc);
      if (col == 0) atomicAdd(&gcnt[cur], cnt);
      acc = 0.f; cnt = 0.f; cur = bb;
    }
    acc += h[(size_t)n * HH + col];
    cnt += 1.f;
  }
  atomicAdd(&g[cur * HH + col], acc);
  if (col == 0) atomicAdd(&gcnt[cur], cnt);
}

// ---------------- final head: mean-pool norm, fc1, BN, relu, out ------------
__global__ __launch_bounds__(256) void k_final(float* __restrict__ g,
                                               const float* __restrict__ gcnt,
                                               const float* __restrict__ fc1w,
                                               const float* __restrict__ fc1b,
                                               const float* __restrict__ gam,
                                               const float* __restrict__ bet,
                                               const float* __restrict__ ow,
                                               const float* __restrict__ ob,
                                               float* __restrict__ out) {
  __shared__ float w_s[HH * HH];
  __shared__ float y_s[BB * HH];
  __shared__ float ls[256], lq[256];
  for (int i = threadIdx.x; i < HH * HH; i += 256) w_s[i] = fc1w[i];
  for (int i = threadIdx.x; i < BB * HH; i += 256) {
    int r = i >> 7;
    g[i] = g[i] / fmaxf(gcnt[r], 1.f);
  }
  __syncthreads();
  int c = threadIdx.x & 127, h2 = threadIdx.x >> 7;
  for (int rr = 0; rr < 64; rr++) {
    int r = h2 * 64 + rr;
    float acc = fc1b[c];
    for (int k = 0; k < HH; k++) acc += g[r * HH + k] * w_s[k * HH + c];
    y_s[r * HH + c] = acc;
  }
  __syncthreads();
  float s = 0.f, sq = 0.f;
  for (int rr = 0; rr < 64; rr++) {
    float v = y_s[(h2 * 64 + rr) * HH + c];
    s += v; sq += v * v;
  }
  ls[threadIdx.x] = s; lq[threadIdx.x] = sq;
  __syncthreads();
  if (h2 == 0) {
    float ss = ls[c] + ls[c + 128], qq = lq[c] + lq[c + 128];
    float mean = ss / (float)BB, var = qq / (float)BB - mean * mean;
    float sc = rsqrtf(var + EPSF) * gam[c];
    ls[c] = sc;
    lq[c] = bet[c] - mean * sc;
  }
  __syncthreads();
  for (int rr = 0; rr < 64; rr++) {
    int r = h2 * 64 + rr;
    y_s[r * HH + c] = fmaxf(y_s[r * HH + c] * ls[c] + lq[c], 0.f);
  }
  __syncthreads();
  int r2 = threadIdx.x >> 1, hf = threadIdx.x & 1;
  float acc = 0.f;
  for (int k = hf * 64; k < hf * 64 + 64; k++) acc += y_s[r2 * HH + k] * ow[k];
  __syncthreads();
  ls[threadIdx.x] = acc;
  __syncthreads();
  if (hf == 0) out[r2] = ls[threadIdx.x] + ls[threadIdx.x + 1] + ob[0];
}

extern "C" void kernel_launch(void* const* d_in, const int* in_sizes, int n_in,
                              void* d_out, int out_size, void* d_ws, size_t ws_size,
                              hipStream_t stream) {
  (void)in_sizes; (void)n_in; (void)out_size; (void)ws_size;
  const float* node_feats = (const float*)d_in[0];
  const int* edge_index = (const int*)d_in[1];
  const float* edge_feats = (const float*)d_in[2];
  const int* batch = (const int*)d_in[3];
  const float* embed_w = (const float*)d_in[4];
  const float* embed_b = (const float*)d_in[5];
  const float* conv_wsrc = (const float*)d_in[6];
  const float* conv_wdst = (const float*)d_in[7];
  const float* conv_we = (const float*)d_in[8];
  const float* conv_b = (const float*)d_in[9];
  const float* bn_gamma = (const float*)d_in[10];
  const float* bn_beta = (const float*)d_in[11];
  const float* fc1_w = (const float*)d_in[12];
  const float* fc1_b = (const float*)d_in[13];
  const float* fc_bn_gamma = (const float*)d_in[14];
  const float* fc_bn_beta = (const float*)d_in[15];
  const float* out_w = (const float*)d_in[16];
  const float* out_b = (const float*)d_in[17];

  char* ws = (char*)d_ws;
  size_t o = 0;
  float* h = (float*)(ws + o);            o += (size_t)NN * HH * 4;        // 51.2 MB
  __hip_bfloat16* hs = (__hip_bfloat16*)(ws + o); o += (size_t)NN * 256 * 2;   // 51.2 MB
  __hip_bfloat16* hd = (__hip_bfloat16*)(ws + o); o += (size_t)NN * 256 * 2;   // 51.2 MB
  float* agg = (float*)(ws + o);          o += (size_t)NN * HH * 4;        // 51.2 MB
  float* ef_s = (float*)(ws + o);         o += (size_t)EE * EDIM * 4;      // 128 MB
  int* src_s = (int*)(ws + o);            o += (size_t)EE * 4;             // 6.4 MB
  int* dst_s = (int*)(ws + o);            o += (size_t)EE * 4;             // 6.4 MB
  int* cnt = (int*)(ws + o);              o += (size_t)NN * 4;             // 0.4 MB
  int* off = (int*)(ws + o);              o += (size_t)NN * 4;             // 0.4 MB
  float* stats = (float*)(ws + o);        o += 256 * 4;
  float* g = (float*)(ws + o);            o += (size_t)BB * HH * 4;
  float* gcnt = (float*)(ws + o);         o += BB * 4;

  const int* src = edge_index;
  const int* dst = edge_index + EE;

  // one-time per launch: counting sort of edges by dst (reused by all layers)
  hipMemsetAsync(cnt, 0, (size_t)NN * 4, stream);
  k_hist<<<2048, 256, 0, stream>>>(dst, cnt);
  k_scan<<<1, 1024, 0, stream>>>(cnt, off);
  k_scatter<<<2048, 256, 0, stream>>>(src, dst, edge_feats, off, src_s, dst_s, ef_s);

  k_embed<<<512, 256, 0, stream>>>(node_feats, embed_w, embed_b, h);

  for (int i = 0; i < 3; i++) {
    k_node_mm<<<dim3(256, 8), 256, 0, stream>>>(h, conv_wsrc + (size_t)i * HH * 256,
                                                conv_wdst + (size_t)i * HH * 256, hs, hd);
    hipMemsetAsync(agg, 0, (size_t)NN * HH * 4, stream);
    hipMemsetAsync(stats, 0, 256 * 4, stream);
    k_edge_sorted<<<2048, 256, 0, stream>>>(hs, hd, ef_s, src_s, dst_s,
                                            conv_we + (size_t)i * EDIM * 256,
                                            conv_b + (size_t)i * 256, agg, 2048 * 4);
    k_bn_stats<<<1024, 256, 0, stream>>>(agg, stats);
    k_bn_fin<<<1, 128, 0, stream>>>(stats, bn_gamma + i * HH, bn_beta + i * HH);
    k_update<<<2048, 256, 0, stream>>>(h, agg, stats);
  }

  hipMemsetAsync(g, 0, (size_t)BB * HH * 4, stream);
  hipMemsetAsync(gcnt, 0, BB * 4, stream);
  k_pool<<<256, 128, 0, stream>>>(h, batch, g, gcnt);
  k_final<<<1, 256, 0, stream>>>(g, gcnt, fc1_w, fc1_b, fc_bn_gamma, fc_bn_beta,
                                 out_w, out_b, (float*)d_out);
}

// Round 4
// 3671.425 us; speedup vs baseline: 2.0130x; 1.1200x over previous
//
#include <hip/hip_runtime.h>
#include <hip/hip_bf16.h>

#define NN 100000
#define EE 1600000
#define HH 128
#define NDIM 91
#define EDIM 20
#define BB 128
#define EPSF 1e-5f

typedef __attribute__((ext_vector_type(8))) short short8v;
typedef __attribute__((ext_vector_type(4))) float f32x4;

__device__ __forceinline__ short f2bs(float x) {
  __hip_bfloat16 b = __float2bfloat16(x);
  return *reinterpret_cast<short*>(&b);
}

// ---------------- embed: h = nf @ W + b  (N x 91 @ 91 x 128) ----------------
__global__ __launch_bounds__(256) void k_embed(const float* __restrict__ nf,
                                               const float* __restrict__ W,
                                               const float* __restrict__ b,
                                               float* __restrict__ h) {
  __shared__ float w_s[NDIM * HH];
  __shared__ float b_s[HH];
  __shared__ float a_s[16 * 92];
  for (int i = threadIdx.x; i < NDIM * HH; i += 256) w_s[i] = W[i];
  if (threadIdx.x < HH) b_s[threadIdx.x] = b[threadIdx.x];
  __syncthreads();
  int col = threadIdx.x & 127, rs = threadIdx.x >> 7;
  for (int base = blockIdx.x * 16; base < NN; base += gridDim.x * 16) {
    int nrows = min(16, NN - base);
    int tot = nrows * NDIM;
    for (int i = threadIdx.x; i < tot; i += 256) {
      int r = i / NDIM;
      a_s[r * 92 + (i - r * NDIM)] = nf[(size_t)base * NDIM + i];
    }
    __syncthreads();
    float acc[8];
#pragma unroll
    for (int r = 0; r < 8; r++) acc[r] = 0.f;
    for (int k = 0; k < NDIM; k++) {
      float w = w_s[k * HH + col];
#pragma unroll
      for (int r = 0; r < 8; r++) acc[r] += a_s[(rs * 8 + r) * 92 + k] * w;
    }
#pragma unroll
    for (int r = 0; r < 8; r++) {
      int row = base + rs * 8 + r;
      if (row < NN) h[(size_t)row * HH + col] = acc[r] + b_s[col];
    }
    __syncthreads();
  }
}

// ------- weight transpose+cast: wt[mat][col][k] = W_mat[k*256+col] (bf16) ---
__global__ __launch_bounds__(256) void k_w2bf(const float* __restrict__ Wsrc,
                                              const float* __restrict__ Wdst,
                                              short* __restrict__ wt) {
  int i = blockIdx.x * 256 + threadIdx.x;  // 0..65535
  if (i >= 2 * 256 * 128) return;
  int mat = i >> 15;
  int r = (i >> 7) & 255;
  int k = i & 127;
  const float* W = mat ? Wdst : Wsrc;
  wt[i] = f2bs(W[k * 256 + r]);
}

// ------------- node_mm via MFMA: out = h(bf16) @ W(bf16), f32 acc ----------
// block: 4 waves, M-tile 64 rows; wave w -> rows [w*16,+16), all 256 cols.
// grid.y selects Wsrc->hs / Wdst->hd.
__global__ __launch_bounds__(256) void k_node_mm(const float* __restrict__ h,
                                                 const short* __restrict__ wt,
                                                 __hip_bfloat16* __restrict__ hs,
                                                 __hip_bfloat16* __restrict__ hd) {
  __shared__ short hlds[64 * 128];  // 16 KB bf16 A-tile
  int mat = blockIdx.y;
  const short* wtm = wt + mat * 256 * 128;
  __hip_bfloat16* out = mat ? hd : hs;
  int base = blockIdx.x * 64;
  int t = threadIdx.x;
#pragma unroll
  for (int p = 0; p < 4; p++) {
    int e0 = (p * 256 + t) * 8;
    int row = e0 >> 7, col = e0 & 127;
    int gr = base + row;
    float4 f0 = make_float4(0.f, 0.f, 0.f, 0.f), f1 = f0;
    if (gr < NN) {
      f0 = *(const float4*)&h[(size_t)gr * 128 + col];
      f1 = *(const float4*)&h[(size_t)gr * 128 + col + 4];
    }
    short8v u;
    u[0] = f2bs(f0.x); u[1] = f2bs(f0.y); u[2] = f2bs(f0.z); u[3] = f2bs(f0.w);
    u[4] = f2bs(f1.x); u[5] = f2bs(f1.y); u[6] = f2bs(f1.z); u[7] = f2bs(f1.w);
    *(short8v*)&hlds[e0] = u;
  }
  __syncthreads();
  int w = t >> 6, l = t & 63;
  int cl = l & 15, kg = l >> 4;
  short8v a[4];
#pragma unroll
  for (int kk = 0; kk < 4; kk++)
    a[kk] = *(const short8v*)&hlds[(w * 16 + cl) * 128 + kk * 32 + kg * 8];
  f32x4 acc[16];
#pragma unroll
  for (int ct = 0; ct < 16; ct++) acc[ct] = (f32x4)(0.f);
#pragma unroll
  for (int ct = 0; ct < 16; ct++) {
#pragma unroll
    for (int kk = 0; kk < 4; kk++) {
      short8v b = *(const short8v*)&wtm[(ct * 16 + cl) * 128 + kk * 32 + kg * 8];
      acc[ct] = __builtin_amdgcn_mfma_f32_16x16x32_bf16(a[kk], b, acc[ct], 0, 0, 0);
    }
  }
#pragma unroll
  for (int ct = 0; ct < 16; ct++) {
#pragma unroll
    for (int r = 0; r < 4; r++) {
      int gr = base + w * 16 + kg * 4 + r;
      if (gr < NN)
        out[(size_t)gr * 256 + ct * 16 + cl] = __float2bfloat16(acc[ct][r]);
    }
  }
}

// ---------------- counting sort by dst: hist, scan, scatter -----------------
__global__ __launch_bounds__(256) void k_hist(const int* __restrict__ dst,
                                              int* __restrict__ cnt) {
  for (int e = blockIdx.x * 256 + threadIdx.x; e < EE; e += gridDim.x * 256)
    atomicAdd(&cnt[dst[e]], 1);
}

__global__ __launch_bounds__(1024) void k_scan(const int* __restrict__ cnt,
                                               int* __restrict__ off) {
  __shared__ int ps[1024];
  int t = threadIdx.x;
  const int R = (NN + 1023) / 1024;
  int b0 = t * R, b1 = min(NN, b0 + R);
  int s = 0;
  for (int i = b0; i < b1; i++) s += cnt[i];
  ps[t] = s;
  __syncthreads();
  for (int d = 1; d < 1024; d <<= 1) {
    int v = (t >= d) ? ps[t - d] : 0;
    __syncthreads();
    ps[t] += v;
    __syncthreads();
  }
  int run = (t == 0) ? 0 : ps[t - 1];
  for (int i = b0; i < b1; i++) {
    off[i] = run;
    run += cnt[i];
  }
}

__global__ __launch_bounds__(256) void k_scatter(const int* __restrict__ src,
                                                 const int* __restrict__ dst,
                                                 const float* __restrict__ ef,
                                                 int* __restrict__ off,
                                                 int* __restrict__ src_s,
                                                 int* __restrict__ dst_s,
                                                 float* __restrict__ ef_s) {
  for (int e = blockIdx.x * 256 + threadIdx.x; e < EE; e += gridDim.x * 256) {
    int d = dst[e];
    int pos = atomicAdd(&off[d], 1);
    src_s[pos] = src[e];
    dst_s[pos] = d;
    const float4* in = (const float4*)&ef[(size_t)e * EDIM];
    float4* outp = (float4*)&ef_s[(size_t)pos * EDIM];
#pragma unroll
    for (int q = 0; q < 5; q++) outp[q] = in[q];
  }
}

__device__ __forceinline__ float softplus_f(float z) {
  float t = __expf(-fabsf(z));
  float l = __logf(1.f + t);
  return (z > 0.f) ? z + l : l;
}

// ---- sorted edge kernel: lane owns ONE col-pair (c, c+128): 40 weight regs.
// 2 waves per slot cover the 128 col-pairs. Segment-accumulate in registers,
// flush via atomicAdd at boundaries. 1-edge software prefetch of src/hs.
__global__ __launch_bounds__(256) void k_edge_sorted(
    const __hip_bfloat16* __restrict__ hs, const __hip_bfloat16* __restrict__ hd,
    const float* __restrict__ ef_s, const int* __restrict__ src_s,
    const int* __restrict__ dst_s, const float* __restrict__ We,
    const float* __restrict__ bias, float* __restrict__ agg, int slots) {
  int lane = threadIdx.x & 63, wv = threadIdx.x >> 6;
  int slot = blockIdx.x * 2 + (wv >> 1);
  int c = (wv & 1) * 64 + lane;  // gate col; softplus col = c+128
  float wa[EDIM], wb[EDIM];
#pragma unroll
  for (int k = 0; k < EDIM; k++) {
    wa[k] = We[k * 256 + c];
    wb[k] = We[k * 256 + 128 + c];
  }
  float ba = bias[c], bp = bias[128 + c];
  int per = (EE + slots - 1) / slots;
  int i0 = slot * per, i1 = min(EE, i0 + per);
  if (i0 >= i1) return;
  int cur = dst_s[i0];
  float hdg = __bfloat162float(hd[(size_t)cur * 256 + c]);
  float hdp = __bfloat162float(hd[(size_t)cur * 256 + 128 + c]);
  int s0 = src_s[i0];
  float hg = __bfloat162float(hs[(size_t)s0 * 256 + c]);
  float hp = __bfloat162float(hs[(size_t)s0 * 256 + 128 + c]);
  float acc = 0.f;
  for (int i = i0; i < i1; i++) {
    int iu = __builtin_amdgcn_readfirstlane(i);
    int inx = (iu + 1 < i1) ? iu + 1 : i1 - 1;
    int s2 = src_s[inx];
    __hip_bfloat16 g2 = hs[(size_t)s2 * 256 + c];
    __hip_bfloat16 p2 = hs[(size_t)s2 * 256 + 128 + c];
    int d = dst_s[iu];
    if (d != cur) {  // wave-uniform branch
      atomicAdd(&agg[(size_t)cur * HH + c], acc);
      acc = 0.f; cur = d;
      hdg = __bfloat162float(hd[(size_t)cur * 256 + c]);
      hdp = __bfloat162float(hd[(size_t)cur * 256 + 128 + c]);
    }
    float za = ba + hg + hdg;
    float zb = bp + hp + hdp;
    const float4* er = (const float4*)&ef_s[(size_t)iu * EDIM];
#pragma unroll
    for (int q = 0; q < 5; q++) {
      float4 ev = er[q];
      za += ev.x * wa[q * 4] + ev.y * wa[q * 4 + 1] + ev.z * wa[q * 4 + 2] + ev.w * wa[q * 4 + 3];
      zb += ev.x * wb[q * 4] + ev.y * wb[q * 4 + 1] + ev.z * wb[q * 4 + 2] + ev.w * wb[q * 4 + 3];
    }
    acc += __fdividef(softplus_f(zb), 1.f + __expf(-za));
    hg = __bfloat162float(g2);
    hp = __bfloat162float(p2);
  }
  atomicAdd(&agg[(size_t)cur * HH + c], acc);
}

// ---------------- BN stats: per-column sum & sumsq over N rows --------------
__global__ __launch_bounds__(256) void k_bn_stats(const float* __restrict__ agg,
                                                  float* __restrict__ stats) {
  int col = threadIdx.x & 127, half = threadIdx.x >> 7;
  float s = 0.f, sq = 0.f;
  for (int row = blockIdx.x * 2 + half; row < NN; row += gridDim.x * 2) {
    float v = agg[(size_t)row * HH + col];
    s += v; sq += v * v;
  }
  __shared__ float ls[256], lq[256];
  ls[threadIdx.x] = s; lq[threadIdx.x] = sq;
  __syncthreads();
  if (half == 0) {
    atomicAdd(&stats[col], ls[col] + ls[col + 128]);
    atomicAdd(&stats[128 + col], lq[col] + lq[col + 128]);
  }
}

__global__ void k_bn_fin(float* stats, const float* __restrict__ gam,
                         const float* __restrict__ bet) {
  int c = threadIdx.x;
  if (c >= HH) return;
  float mean = stats[c] / (float)NN;
  float var = stats[HH + c] / (float)NN - mean * mean;
  float sc = rsqrtf(var + EPSF) * gam[c];
  stats[c] = sc;
  stats[HH + c] = bet[c] - mean * sc;
}

// ---------------- h = relu(h + agg*scale + shift) ---------------------------
__global__ __launch_bounds__(256) void k_update(float* __restrict__ h,
                                                const float* __restrict__ agg,
                                                const float* __restrict__ stats) {
  for (size_t i = (size_t)blockIdx.x * blockDim.x + threadIdx.x; i < (size_t)NN * HH;
       i += (size_t)gridDim.x * blockDim.x) {
    int c = (int)(i & 127);
    float v = h[i] + agg[i] * stats[c] + stats[128 + c];
    h[i] = fmaxf(v, 0.f);
  }
}

// ---------------- pooling: contiguous chunk per block, register acc ---------
__global__ void k_pool(const float* __restrict__ h, const int* __restrict__ batch,
                       float* __restrict__ g, float* __restrict__ gcnt) {
  int col = threadIdx.x;  // 128
  int chunk = (NN + gridDim.x - 1) / gridDim.x;
  int n0 = blockIdx.x * chunk, n1 = min(NN, n0 + chunk);
  if (n0 >= n1) return;
  int cur = batch[n0];
  float acc = 0.f, cnt = 0.f;
  for (int n = n0; n < n1; n++) {
    int bb = batch[n];
    if (bb != cur) {
      atomicAdd(&g[cur * HH + col], acc);
      if (col == 0) atomicAdd(&gcnt[cur], cnt);
      acc = 0.f; cnt = 0.f; cur = bb;
    }
    acc += h[(size_t)n * HH + col];
    cnt += 1.f;
  }
  atomicAdd(&g[cur * HH + col], acc);
  if (col == 0) atomicAdd(&gcnt[cur], cnt);
}

// ---------------- final head: mean-pool norm, fc1, BN, relu, out ------------
__global__ __launch_bounds__(256) void k_final(float* __restrict__ g,
                                               const float* __restrict__ gcnt,
                                               const float* __restrict__ fc1w,
                                               const float* __restrict__ fc1b,
                                               const float* __restrict__ gam,
                                               const float* __restrict__ bet,
                                               const float* __restrict__ ow,
                                               const float* __restrict__ ob,
                                               float* __restrict__ out) {
  __shared__ float w_s[HH * HH];
  __shared__ float y_s[BB * HH];
  __shared__ float ls[256], lq[256];
  for (int i = threadIdx.x; i < HH * HH; i += 256) w_s[i] = fc1w[i];
  for (int i = threadIdx.x; i < BB * HH; i += 256) {
    int r = i >> 7;
    g[i] = g[i] / fmaxf(gcnt[r], 1.f);
  }
  __syncthreads();
  int c = threadIdx.x & 127, h2 = threadIdx.x >> 7;
  for (int rr = 0; rr < 64; rr++) {
    int r = h2 * 64 + rr;
    float acc = fc1b[c];
    for (int k = 0; k < HH; k++) acc += g[r * HH + k] * w_s[k * HH + c];
    y_s[r * HH + c] = acc;
  }
  __syncthreads();
  float s = 0.f, sq = 0.f;
  for (int rr = 0; rr < 64; rr++) {
    float v = y_s[(h2 * 64 + rr) * HH + c];
    s += v; sq += v * v;
  }
  ls[threadIdx.x] = s; lq[threadIdx.x] = sq;
  __syncthreads();
  if (h2 == 0) {
    float ss = ls[c] + ls[c + 128], qq = lq[c] + lq[c + 128];
    float mean = ss / (float)BB, var = qq / (float)BB - mean * mean;
    float sc = rsqrtf(var + EPSF) * gam[c];
    ls[c] = sc;
    lq[c] = bet[c] - mean * sc;
  }
  __syncthreads();
  for (int rr = 0; rr < 64; rr++) {
    int r = h2 * 64 + rr;
    y_s[r * HH + c] = fmaxf(y_s[r * HH + c] * ls[c] + lq[c], 0.f);
  }
  __syncthreads();
  int r2 = threadIdx.x >> 1, hf = threadIdx.x & 1;
  float acc = 0.f;
  for (int k = hf * 64; k < hf * 64 + 64; k++) acc += y_s[r2 * HH + k] * ow[k];
  __syncthreads();
  ls[threadIdx.x] = acc;
  __syncthreads();
  if (hf == 0) out[r2] = ls[threadIdx.x] + ls[threadIdx.x + 1] + ob[0];
}

extern "C" void kernel_launch(void* const* d_in, const int* in_sizes, int n_in,
                              void* d_out, int out_size, void* d_ws, size_t ws_size,
                              hipStream_t stream) {
  (void)in_sizes; (void)n_in; (void)out_size; (void)ws_size;
  const float* node_feats = (const float*)d_in[0];
  const int* edge_index = (const int*)d_in[1];
  const float* edge_feats = (const float*)d_in[2];
  const int* batch = (const int*)d_in[3];
  const float* embed_w = (const float*)d_in[4];
  const float* embed_b = (const float*)d_in[5];
  const float* conv_wsrc = (const float*)d_in[6];
  const float* conv_wdst = (const float*)d_in[7];
  const float* conv_we = (const float*)d_in[8];
  const float* conv_b = (const float*)d_in[9];
  const float* bn_gamma = (const float*)d_in[10];
  const float* bn_beta = (const float*)d_in[11];
  const float* fc1_w = (const float*)d_in[12];
  const float* fc1_b = (const float*)d_in[13];
  const float* fc_bn_gamma = (const float*)d_in[14];
  const float* fc_bn_beta = (const float*)d_in[15];
  const float* out_w = (const float*)d_in[16];
  const float* out_b = (const float*)d_in[17];

  char* ws = (char*)d_ws;
  size_t o = 0;
  float* h = (float*)(ws + o);            o += (size_t)NN * HH * 4;        // 51.2 MB
  __hip_bfloat16* hs = (__hip_bfloat16*)(ws + o); o += (size_t)NN * 256 * 2;   // 51.2 MB
  __hip_bfloat16* hd = (__hip_bfloat16*)(ws + o); o += (size_t)NN * 256 * 2;   // 51.2 MB
  float* agg = (float*)(ws + o);          o += (size_t)NN * HH * 4;        // 51.2 MB
  float* ef_s = (float*)(ws + o);         o += (size_t)EE * EDIM * 4;      // 128 MB
  int* src_s = (int*)(ws + o);            o += (size_t)EE * 4;             // 6.4 MB
  int* dst_s = (int*)(ws + o);            o += (size_t)EE * 4;             // 6.4 MB
  int* cnt = (int*)(ws + o);              o += (size_t)NN * 4;
  int* off = (int*)(ws + o);              o += (size_t)NN * 4;
  short* wt = (short*)(ws + o);           o += (size_t)2 * 256 * 128 * 2;  // 131 KB
  float* stats = (float*)(ws + o);        o += 256 * 4;
  float* g = (float*)(ws + o);            o += (size_t)BB * HH * 4;
  float* gcnt = (float*)(ws + o);         o += BB * 4;

  const int* src = edge_index;
  const int* dst = edge_index + EE;

  // one-time per launch: counting sort of edges by dst (reused by all layers)
  hipMemsetAsync(cnt, 0, (size_t)NN * 4, stream);
  k_hist<<<2048, 256, 0, stream>>>(dst, cnt);
  k_scan<<<1, 1024, 0, stream>>>(cnt, off);
  k_scatter<<<2048, 256, 0, stream>>>(src, dst, edge_feats, off, src_s, dst_s, ef_s);

  k_embed<<<512, 256, 0, stream>>>(node_feats, embed_w, embed_b, h);

  for (int i = 0; i < 3; i++) {
    k_w2bf<<<256, 256, 0, stream>>>(conv_wsrc + (size_t)i * HH * 256,
                                    conv_wdst + (size_t)i * HH * 256, wt);
    k_node_mm<<<dim3((NN + 63) / 64, 2), 256, 0, stream>>>(h, wt, hs, hd);
    hipMemsetAsync(agg, 0, (size_t)NN * HH * 4, stream);
    hipMemsetAsync(stats, 0, 256 * 4, stream);
    k_edge_sorted<<<2048, 256, 0, stream>>>(hs, hd, ef_s, src_s, dst_s,
                                            conv_we + (size_t)i * EDIM * 256,
                                            conv_b + (size_t)i * 256, agg, 2048 * 2);
    k_bn_stats<<<1024, 256, 0, stream>>>(agg, stats);
    k_bn_fin<<<1, 128, 0, stream>>>(stats, bn_gamma + i * HH, bn_beta + i * HH);
    k_update<<<2048, 256, 0, stream>>>(h, agg, stats);
  }

  hipMemsetAsync(g, 0, (size_t)BB * HH * 4, stream);
  hipMemsetAsync(gcnt, 0, BB * 4, stream);
  k_pool<<<256, 128, 0, stream>>>(h, batch, g, gcnt);
  k_final<<<1, 256, 0, stream>>>(g, gcnt, fc1_w, fc1_b, fc_bn_gamma, fc_bn_beta,
                                 out_w, out_b, (float*)d_out);
}

// Round 5
// 3040.918 us; speedup vs baseline: 2.4303x; 1.2073x over previous
//
#include <hip/hip_runtime.h>
#include <hip/hip_bf16.h>

#define NN 100000
#define EE 1600000
#define HH 128
#define NDIM 91
#define EDIM 20
#define BB 128
#define EPSF 1e-5f
#define EB 32  // edges per batch in k_edge_mfma

typedef __attribute__((ext_vector_type(8))) short short8v;
typedef __attribute__((ext_vector_type(4))) float f32x4;

__device__ __forceinline__ short f2bs(float x) {
  __hip_bfloat16 b = __float2bfloat16(x);
  return *reinterpret_cast<short*>(&b);
}

// ---------------- embed: h = nf @ W + b  (N x 91 @ 91 x 128) ----------------
__global__ __launch_bounds__(256) void k_embed(const float* __restrict__ nf,
                                               const float* __restrict__ W,
                                               const float* __restrict__ b,
                                               float* __restrict__ h) {
  __shared__ float w_s[NDIM * HH];
  __shared__ float b_s[HH];
  __shared__ float a_s[16 * 92];
  for (int i = threadIdx.x; i < NDIM * HH; i += 256) w_s[i] = W[i];
  if (threadIdx.x < HH) b_s[threadIdx.x] = b[threadIdx.x];
  __syncthreads();
  int col = threadIdx.x & 127, rs = threadIdx.x >> 7;
  for (int base = blockIdx.x * 16; base < NN; base += gridDim.x * 16) {
    int nrows = min(16, NN - base);
    int tot = nrows * NDIM;
    for (int i = threadIdx.x; i < tot; i += 256) {
      int r = i / NDIM;
      a_s[r * 92 + (i - r * NDIM)] = nf[(size_t)base * NDIM + i];
    }
    __syncthreads();
    float acc[8];
#pragma unroll
    for (int r = 0; r < 8; r++) acc[r] = 0.f;
    for (int k = 0; k < NDIM; k++) {
      float w = w_s[k * HH + col];
#pragma unroll
      for (int r = 0; r < 8; r++) acc[r] += a_s[(rs * 8 + r) * 92 + k] * w;
    }
#pragma unroll
    for (int r = 0; r < 8; r++) {
      int row = base + rs * 8 + r;
      if (row < NN) h[(size_t)row * HH + col] = acc[r] + b_s[col];
    }
    __syncthreads();
  }
}

// ------- weight transpose+cast: wt[mat][col][k] = W_mat[k*256+col] (bf16) ---
__global__ __launch_bounds__(256) void k_w2bf(const float* __restrict__ Wsrc,
                                              const float* __restrict__ Wdst,
                                              short* __restrict__ wt) {
  int i = blockIdx.x * 256 + threadIdx.x;  // 0..65535
  if (i >= 2 * 256 * 128) return;
  int mat = i >> 15;
  int r = (i >> 7) & 255;
  int k = i & 127;
  const float* W = mat ? Wdst : Wsrc;
  wt[i] = f2bs(W[k * 256 + r]);
}

// ------- edge-weight transpose+cast: Web[c][k] bf16, k=20 -> bias, pad 0 ----
__global__ __launch_bounds__(256) void k_we2bf(const float* __restrict__ We,
                                               const float* __restrict__ bias,
                                               short* __restrict__ Web) {
  int i = blockIdx.x * 256 + threadIdx.x;  // 0..8191
  if (i >= 256 * 32) return;
  int c = i >> 5, k = i & 31;
  float v = (k < EDIM) ? We[k * 256 + c] : (k == EDIM ? bias[c] : 0.f);
  Web[i] = f2bs(v);
}

// ------------- node_mm via MFMA: out = h(bf16) @ W(bf16), f32 acc ----------
__global__ __launch_bounds__(256) void k_node_mm(const float* __restrict__ h,
                                                 const short* __restrict__ wt,
                                                 __hip_bfloat16* __restrict__ hs,
                                                 __hip_bfloat16* __restrict__ hd) {
  __shared__ short hlds[64 * 128];  // 16 KB bf16 A-tile
  int mat = blockIdx.y;
  const short* wtm = wt + mat * 256 * 128;
  __hip_bfloat16* out = mat ? hd : hs;
  int base = blockIdx.x * 64;
  int t = threadIdx.x;
#pragma unroll
  for (int p = 0; p < 4; p++) {
    int e0 = (p * 256 + t) * 8;
    int row = e0 >> 7, col = e0 & 127;
    int gr = base + row;
    float4 f0 = make_float4(0.f, 0.f, 0.f, 0.f), f1 = f0;
    if (gr < NN) {
      f0 = *(const float4*)&h[(size_t)gr * 128 + col];
      f1 = *(const float4*)&h[(size_t)gr * 128 + col + 4];
    }
    short8v u;
    u[0] = f2bs(f0.x); u[1] = f2bs(f0.y); u[2] = f2bs(f0.z); u[3] = f2bs(f0.w);
    u[4] = f2bs(f1.x); u[5] = f2bs(f1.y); u[6] = f2bs(f1.z); u[7] = f2bs(f1.w);
    *(short8v*)&hlds[e0] = u;
  }
  __syncthreads();
  int w = t >> 6, l = t & 63;
  int cl = l & 15, kg = l >> 4;
  short8v a[4];
#pragma unroll
  for (int kk = 0; kk < 4; kk++)
    a[kk] = *(const short8v*)&hlds[(w * 16 + cl) * 128 + kk * 32 + kg * 8];
  f32x4 acc[16];
#pragma unroll
  for (int ct = 0; ct < 16; ct++) acc[ct] = (f32x4)(0.f);
#pragma unroll
  for (int ct = 0; ct < 16; ct++) {
#pragma unroll
    for (int kk = 0; kk < 4; kk++) {
      short8v b = *(const short8v*)&wtm[(ct * 16 + cl) * 128 + kk * 32 + kg * 8];
      acc[ct] = __builtin_amdgcn_mfma_f32_16x16x32_bf16(a[kk], b, acc[ct], 0, 0, 0);
    }
  }
#pragma unroll
  for (int ct = 0; ct < 16; ct++) {
#pragma unroll
    for (int r = 0; r < 4; r++) {
      int gr = base + w * 16 + kg * 4 + r;
      if (gr < NN)
        out[(size_t)gr * 256 + ct * 16 + cl] = __float2bfloat16(acc[ct][r]);
    }
  }
}

// ---------------- counting sort by dst: hist, scan, scatter -----------------
__global__ __launch_bounds__(256) void k_hist(const int* __restrict__ dst,
                                              int* __restrict__ cnt) {
  for (int e = blockIdx.x * 256 + threadIdx.x; e < EE; e += gridDim.x * 256)
    atomicAdd(&cnt[dst[e]], 1);
}

__global__ __launch_bounds__(1024) void k_scan(const int* __restrict__ cnt,
                                               int* __restrict__ off) {
  __shared__ int ps[1024];
  int t = threadIdx.x;
  const int R = (NN + 1023) / 1024;
  int b0 = t * R, b1 = min(NN, b0 + R);
  int s = 0;
  for (int i = b0; i < b1; i++) s += cnt[i];
  ps[t] = s;
  __syncthreads();
  for (int d = 1; d < 1024; d <<= 1) {
    int v = (t >= d) ? ps[t - d] : 0;
    __syncthreads();
    ps[t] += v;
    __syncthreads();
  }
  int run = (t == 0) ? 0 : ps[t - 1];
  for (int i = b0; i < b1; i++) {
    off[i] = run;
    run += cnt[i];
  }
}

__global__ __launch_bounds__(256) void k_scatter(const int* __restrict__ src,
                                                 const int* __restrict__ dst,
                                                 const float* __restrict__ ef,
                                                 int* __restrict__ off,
                                                 int* __restrict__ src_s,
                                                 int* __restrict__ dst_s,
                                                 float* __restrict__ ef_s) {
  for (int e = blockIdx.x * 256 + threadIdx.x; e < EE; e += gridDim.x * 256) {
    int d = dst[e];
    int pos = atomicAdd(&off[d], 1);
    src_s[pos] = src[e];
    dst_s[pos] = d;
    const float4* in = (const float4*)&ef[(size_t)e * EDIM];
    float4* outp = (float4*)&ef_s[(size_t)pos * EDIM];
#pragma unroll
    for (int q = 0; q < 5; q++) outp[q] = in[q];
  }
}

__device__ __forceinline__ float softplus_f(float z) {
  float t = __expf(-fabsf(z));
  float l = __logf(1.f + t);
  return (z > 0.f) ? z + l : l;
}

// ---- edge kernel v3: per 32-edge batch: stage ef->bf16 LDS; MFMA ez=ef@Web
// ---- (bias folded via k=20 column of 1s); column phase: lane owns col-pair
// ---- (c, c+128), run-based register segment-sum, atomic flush on dst change.
__global__ __launch_bounds__(256) void k_edge_mfma(
    const __hip_bfloat16* __restrict__ hs, const __hip_bfloat16* __restrict__ hd,
    const float* __restrict__ ef_s, const int* __restrict__ src_s,
    const int* __restrict__ dst_s, const short* __restrict__ Web,
    float* __restrict__ agg, int per) {
  __shared__ short ef_lds[EB * 32];    // 2 KB  [edge][k] bf16
  __shared__ float ez_lds[EB][260];    // 33.3 KB (pad 260 to spread banks)
  __shared__ int src_lds[EB];
  __shared__ int dst_lds[EB];
  int i0 = blockIdx.x * per;
  if (i0 >= EE) return;
  int i1 = min(EE, i0 + per);
  int t = threadIdx.x;
  int w = t >> 6, l = t & 63;
  int cl = l & 15, kg = l >> 4;
  // resident B fragments: this wave's 64 output cols [w*64, w*64+64)
  short8v bfr[4];
#pragma unroll
  for (int ct = 0; ct < 4; ct++)
    bfr[ct] = *(const short8v*)&Web[(w * 64 + ct * 16 + cl) * 32 + kg * 8];
  // column-phase persistent state
  int c = t & 127, half = t >> 7;
  int cur = dst_s[i0];
  float hd_g = __bfloat162float(hd[(size_t)cur * 256 + c]);
  float hd_p = __bfloat162float(hd[(size_t)cur * 256 + 128 + c]);
  float acc = 0.f;

  for (int bb = i0; bb < i1; bb += EB) {
    // ---- stage ef batch (coalesced f32 reads -> bf16 LDS) ----
    for (int i = t; i < EB * EDIM; i += 256) {
      int e = i / EDIM;
      int k = i - e * EDIM;
      float v = (bb + e < EE) ? ef_s[(size_t)bb * EDIM + i] : 0.f;
      ef_lds[e * 32 + k] = f2bs(v);
    }
    for (int i = t; i < EB * 12; i += 256) {  // k = 20..31: bias-hook + pad
      int e = i / 12;
      int k = 20 + (i - e * 12);
      ef_lds[e * 32 + k] = (k == EDIM) ? f2bs(1.f) : (short)0;
    }
    if (t < EB) {
      int ge = bb + t;
      src_lds[t] = (ge < i1) ? src_s[ge] : 0;
      dst_lds[t] = (ge < i1) ? dst_s[ge] : -1;
    }
    __syncthreads();
    // ---- MFMA phase: ez[e][col] = ef[e][:] @ Web[col][:] ----
#pragma unroll
    for (int mt = 0; mt < 2; mt++) {
      short8v a = *(const short8v*)&ef_lds[(mt * 16 + cl) * 32 + kg * 8];
#pragma unroll
      for (int ct = 0; ct < 4; ct++) {
        f32x4 z = __builtin_amdgcn_mfma_f32_16x16x32_bf16(a, bfr[ct], (f32x4)(0.f), 0, 0, 0);
#pragma unroll
        for (int r = 0; r < 4; r++)
          ez_lds[mt * 16 + kg * 4 + r][w * 64 + ct * 16 + cl] = z[r];
      }
    }
    __syncthreads();
    // ---- column phase: threads split 2 halves x 128 cols; 16 edges each ----
    int e0l = half * 16;
#pragma unroll 4
    for (int e = e0l; e < e0l + 16; e++) {
      if (bb + e >= i1) break;  // wave-uniform
      int d = dst_lds[e];
      int s = src_lds[e];
      if (d != cur) {  // wave-uniform
        atomicAdd(&agg[(size_t)cur * HH + c], acc);
        acc = 0.f;
        cur = d;
        hd_g = __bfloat162float(hd[(size_t)cur * 256 + c]);
        hd_p = __bfloat162float(hd[(size_t)cur * 256 + 128 + c]);
      }
      float zg = ez_lds[e][c] + __bfloat162float(hs[(size_t)s * 256 + c]) + hd_g;
      float zp = ez_lds[e][128 + c] + __bfloat162float(hs[(size_t)s * 256 + 128 + c]) + hd_p;
      acc += __fdividef(softplus_f(zp), 1.f + __expf(-zg));
    }
    __syncthreads();
  }
  atomicAdd(&agg[(size_t)cur * HH + c], acc);
}

// ---------------- BN stats: per-column sum & sumsq over N rows --------------
__global__ __launch_bounds__(256) void k_bn_stats(const float* __restrict__ agg,
                                                  float* __restrict__ stats) {
  int col = threadIdx.x & 127, half = threadIdx.x >> 7;
  float s = 0.f, sq = 0.f;
  for (int row = blockIdx.x * 2 + half; row < NN; row += gridDim.x * 2) {
    float v = agg[(size_t)row * HH + col];
    s += v; sq += v * v;
  }
  __shared__ float ls[256], lq[256];
  ls[threadIdx.x] = s; lq[threadIdx.x] = sq;
  __syncthreads();
  if (half == 0) {
    atomicAdd(&stats[col], ls[col] + ls[col + 128]);
    atomicAdd(&stats[128 + col], lq[col] + lq[col + 128]);
  }
}

__global__ void k_bn_fin(float* stats, const float* __restrict__ gam,
                         const float* __restrict__ bet) {
  int c = threadIdx.x;
  if (c >= HH) return;
  float mean = stats[c] / (float)NN;
  float var = stats[HH + c] / (float)NN - mean * mean;
  float sc = rsqrtf(var + EPSF) * gam[c];
  stats[c] = sc;
  stats[HH + c] = bet[c] - mean * sc;
}

// ---------------- h = relu(h + agg*scale + shift) ---------------------------
__global__ __launch_bounds__(256) void k_update(float* __restrict__ h,
                                                const float* __restrict__ agg,
                                                const float* __restrict__ stats) {
  for (size_t i = (size_t)blockIdx.x * blockDim.x + threadIdx.x; i < (size_t)NN * HH;
       i += (size_t)gridDim.x * blockDim.x) {
    int c = (int)(i & 127);
    float v = h[i] + agg[i] * stats[c] + stats[128 + c];
    h[i] = fmaxf(v, 0.f);
  }
}

// ---------------- pooling: contiguous chunk per block, register acc ---------
__global__ void k_pool(const float* __restrict__ h, const int* __restrict__ batch,
                       float* __restrict__ g, float* __restrict__ gcnt) {
  int col = threadIdx.x;  // 128
  int chunk = (NN + gridDim.x - 1) / gridDim.x;
  int n0 = blockIdx.x * chunk, n1 = min(NN, n0 + chunk);
  if (n0 >= n1) return;
  int cur = batch[n0];
  float acc = 0.f, cnt = 0.f;
  for (int n = n0; n < n1; n++) {
    int bb = batch[n];
    if (bb != cur) {
      atomicAdd(&g[cur * HH + col], acc);
      if (col == 0) atomicAdd(&gcnt[cur], cnt);
      acc = 0.f; cnt = 0.f; cur = bb;
    }
    acc += h[(size_t)n * HH + col];
    cnt += 1.f;
  }
  atomicAdd(&g[cur * HH + col], acc);
  if (col == 0) atomicAdd(&gcnt[cur], cnt);
}

// ---------------- final head: mean-pool norm, fc1, BN, relu, out ------------
__global__ __launch_bounds__(256) void k_final(float* __restrict__ g,
                                               const float* __restrict__ gcnt,
                                               const float* __restrict__ fc1w,
                                               const float* __restrict__ fc1b,
                                               const float* __restrict__ gam,
                                               const float* __restrict__ bet,
                                               const float* __restrict__ ow,
                                               const float* __restrict__ ob,
                                               float* __restrict__ out) {
  __shared__ float w_s[HH * HH];
  __shared__ float y_s[BB * HH];
  __shared__ float ls[256], lq[256];
  for (int i = threadIdx.x; i < HH * HH; i += 256) w_s[i] = fc1w[i];
  for (int i = threadIdx.x; i < BB * HH; i += 256) {
    int r = i >> 7;
    g[i] = g[i] / fmaxf(gcnt[r], 1.f);
  }
  __syncthreads();
  int c = threadIdx.x & 127, h2 = threadIdx.x >> 7;
  for (int rr = 0; rr < 64; rr++) {
    int r = h2 * 64 + rr;
    float acc = fc1b[c];
    for (int k = 0; k < HH; k++) acc += g[r * HH + k] * w_s[k * HH + c];
    y_s[r * HH + c] = acc;
  }
  __syncthreads();
  float s = 0.f, sq = 0.f;
  for (int rr = 0; rr < 64; rr++) {
    float v = y_s[(h2 * 64 + rr) * HH + c];
    s += v; sq += v * v;
  }
  ls[threadIdx.x] = s; lq[threadIdx.x] = sq;
  __syncthreads();
  if (h2 == 0) {
    float ss = ls[c] + ls[c + 128], qq = lq[c] + lq[c + 128];
    float mean = ss / (float)BB, var = qq / (float)BB - mean * mean;
    float sc = rsqrtf(var + EPSF) * gam[c];
    ls[c] = sc;
    lq[c] = bet[c] - mean * sc;
  }
  __syncthreads();
  for (int rr = 0; rr < 64; rr++) {
    int r = h2 * 64 + rr;
    y_s[r * HH + c] = fmaxf(y_s[r * HH + c] * ls[c] + lq[c], 0.f);
  }
  __syncthreads();
  int r2 = threadIdx.x >> 1, hf = threadIdx.x & 1;
  float acc = 0.f;
  for (int k = hf * 64; k < hf * 64 + 64; k++) acc += y_s[r2 * HH + k] * ow[k];
  __syncthreads();
  ls[threadIdx.x] = acc;
  __syncthreads();
  if (hf == 0) out[r2] = ls[threadIdx.x] + ls[threadIdx.x + 1] + ob[0];
}

extern "C" void kernel_launch(void* const* d_in, const int* in_sizes, int n_in,
                              void* d_out, int out_size, void* d_ws, size_t ws_size,
                              hipStream_t stream) {
  (void)in_sizes; (void)n_in; (void)out_size; (void)ws_size;
  const float* node_feats = (const float*)d_in[0];
  const int* edge_index = (const int*)d_in[1];
  const float* edge_feats = (const float*)d_in[2];
  const int* batch = (const int*)d_in[3];
  const float* embed_w = (const float*)d_in[4];
  const float* embed_b = (const float*)d_in[5];
  const float* conv_wsrc = (const float*)d_in[6];
  const float* conv_wdst = (const float*)d_in[7];
  const float* conv_we = (const float*)d_in[8];
  const float* conv_b = (const float*)d_in[9];
  const float* bn_gamma = (const float*)d_in[10];
  const float* bn_beta = (const float*)d_in[11];
  const float* fc1_w = (const float*)d_in[12];
  const float* fc1_b = (const float*)d_in[13];
  const float* fc_bn_gamma = (const float*)d_in[14];
  const float* fc_bn_beta = (const float*)d_in[15];
  const float* out_w = (const float*)d_in[16];
  const float* out_b = (const float*)d_in[17];

  char* ws = (char*)d_ws;
  size_t o = 0;
  float* h = (float*)(ws + o);            o += (size_t)NN * HH * 4;
  __hip_bfloat16* hs = (__hip_bfloat16*)(ws + o); o += (size_t)NN * 256 * 2;
  __hip_bfloat16* hd = (__hip_bfloat16*)(ws + o); o += (size_t)NN * 256 * 2;
  float* agg = (float*)(ws + o);          o += (size_t)NN * HH * 4;
  float* ef_s = (float*)(ws + o);         o += (size_t)EE * EDIM * 4;
  int* src_s = (int*)(ws + o);            o += (size_t)EE * 4;
  int* dst_s = (int*)(ws + o);            o += (size_t)EE * 4;
  int* cnt = (int*)(ws + o);              o += (size_t)NN * 4;
  int* off = (int*)(ws + o);              o += (size_t)NN * 4;
  short* wt = (short*)(ws + o);           o += (size_t)2 * 256 * 128 * 2;
  short* Web = (short*)(ws + o);          o += (size_t)256 * 32 * 2;
  float* stats = (float*)(ws + o);        o += 256 * 4;
  float* g = (float*)(ws + o);            o += (size_t)BB * HH * 4;
  float* gcnt = (float*)(ws + o);         o += BB * 4;

  const int* src = edge_index;
  const int* dst = edge_index + EE;

  // one-time per launch: counting sort of edges by dst (reused by all layers)
  hipMemsetAsync(cnt, 0, (size_t)NN * 4, stream);
  k_hist<<<2048, 256, 0, stream>>>(dst, cnt);
  k_scan<<<1, 1024, 0, stream>>>(cnt, off);
  k_scatter<<<2048, 256, 0, stream>>>(src, dst, edge_feats, off, src_s, dst_s, ef_s);

  k_embed<<<512, 256, 0, stream>>>(node_feats, embed_w, embed_b, h);

  // per-block edge range: 1024 blocks (exactly 4/CU LDS-resident), 32-aligned
  const int nblk = 1024;
  const int per = (((EE + nblk - 1) / nblk) + EB - 1) / EB * EB;  // 1568

  for (int i = 0; i < 3; i++) {
    k_w2bf<<<256, 256, 0, stream>>>(conv_wsrc + (size_t)i * HH * 256,
                                    conv_wdst + (size_t)i * HH * 256, wt);
    k_we2bf<<<32, 256, 0, stream>>>(conv_we + (size_t)i * EDIM * 256,
                                    conv_b + (size_t)i * 256, Web);
    k_node_mm<<<dim3((NN + 63) / 64, 2), 256, 0, stream>>>(h, wt, hs, hd);
    hipMemsetAsync(agg, 0, (size_t)NN * HH * 4, stream);
    hipMemsetAsync(stats, 0, 256 * 4, stream);
    k_edge_mfma<<<nblk, 256, 0, stream>>>(hs, hd, ef_s, src_s, dst_s, Web, agg, per);
    k_bn_stats<<<1024, 256, 0, stream>>>(agg, stats);
    k_bn_fin<<<1, 128, 0, stream>>>(stats, bn_gamma + i * HH, bn_beta + i * HH);
    k_update<<<2048, 256, 0, stream>>>(h, agg, stats);
  }

  hipMemsetAsync(g, 0, (size_t)BB * HH * 4, stream);
  hipMemsetAsync(gcnt, 0, BB * 4, stream);
  k_pool<<<256, 128, 0, stream>>>(h, batch, g, gcnt);
  k_final<<<1, 256, 0, stream>>>(g, gcnt, fc1_w, fc1_b, fc_bn_gamma, fc_bn_beta,
                                 out_w, out_b, (float*)d_out);
}